// Round 4
// baseline (448.436 us; speedup 1.0000x reference)
//
#include <hip/hip_runtime.h>
#include <math.h>

#define D_MODEL 96
#define D_INNER 192
#define DT_RANK 6
#define K4      4
#define BSZ     4
#define HH      128
#define WW      128
#define LL      16384  // HH*WW

#define LOG2E 1.4426950408889634f
#define LN2   0.6931471805599453f

#if __has_builtin(__builtin_amdgcn_exp2f)
__device__ __forceinline__ float fexp2_(float x){ return __builtin_amdgcn_exp2f(x); }
#else
__device__ __forceinline__ float fexp2_(float x){ return exp2f(x); }
#endif
#if __has_builtin(__builtin_amdgcn_logf)
__device__ __forceinline__ float flog2_(float x){ return __builtin_amdgcn_logf(x); }
#else
__device__ __forceinline__ float flog2_(float x){ return log2f(x); }
#endif
#if __has_builtin(__builtin_amdgcn_rcpf)
__device__ __forceinline__ float frcp_(float x){ return __builtin_amdgcn_rcpf(x); }
#else
__device__ __forceinline__ float frcp_(float x){ return 1.0f/x; }
#endif

__device__ __forceinline__ float softplus_fast(float x){
    return fmaxf(x, 0.0f) + LN2 * flog2_(1.0f + fexp2_(-LOG2E * fabsf(x)));
}
__device__ __forceinline__ float silu_fast(float x){
    return x * frcp_(1.0f + fexp2_(-LOG2E * x));
}

// ---------------------------------------------------------------- kernel 1
// z0[b,d,l] = sum_c in_w[d,c] * x[b,c,l] + in_b[d]
// Streaming form: each x value loaded ONCE per thread, 48 accumulators.
__global__ __launch_bounds__(256) void k_inproj(const float* __restrict__ x,
                                                const float* __restrict__ in_w,
                                                const float* __restrict__ in_b,
                                                float* __restrict__ z0) {
    const int blk = blockIdx.x;           // 1024 = 4 b * 256 chunks
    const int b  = blk >> 8;
    const int l0 = (blk & 255) << 6;
    const int p = threadIdx.x & 63;
    const int g = __builtin_amdgcn_readfirstlane(threadIdx.x >> 6);  // 0..3
    const float* xb = x + (size_t)b * D_MODEL * LL + l0 + p;
    float* zb = z0 + (size_t)b * D_INNER * LL + l0 + p;
    const int d0 = g * 48;
    float acc[48];
    #pragma unroll
    for (int j = 0; j < 48; ++j) acc[j] = in_b[d0 + j];
    const float* w0 = in_w + (size_t)d0 * D_MODEL;
    #pragma unroll 4
    for (int c = 0; c < D_MODEL; ++c) {
        float v = xb[(size_t)c * LL];
        #pragma unroll
        for (int j = 0; j < 48; ++j)
            acc[j] = fmaf(w0[j * D_MODEL + c], v, acc[j]);
    }
    #pragma unroll
    for (int j = 0; j < 48; ++j) zb[(size_t)(d0 + j) * LL] = acc[j];
}

// ---------------------------------------------------------------- kernel 2
// depthwise 3x3 SAME conv + bias + SiLU -> z (row-major) and zT (transposed)
__global__ __launch_bounds__(256) void k_dwconv(const float* __restrict__ z0,
                                                const float* __restrict__ dw_w,
                                                const float* __restrict__ dw_b,
                                                float* __restrict__ z,
                                                float* __restrict__ zT) {
    __shared__ float tin[34][34];
    __shared__ float tout[32][33];
    const int blk  = blockIdx.x;          // 768*16
    const int tile = blk & 15;
    const int bd   = blk >> 4;            // b*192 + d
    const int d    = bd % D_INNER;
    const int h0 = (tile >> 2) << 5, w0 = (tile & 3) << 5;
    const float* src = z0 + (size_t)bd * LL;
    for (int i = threadIdx.x; i < 34 * 34; i += 256) {
        int r = i / 34, c = i - r * 34;
        int hh = h0 + r - 1, ww = w0 + c - 1;
        float v = 0.0f;
        if (hh >= 0 && hh < HH && ww >= 0 && ww < WW) v = src[hh * WW + ww];
        tin[r][c] = v;
    }
    __syncthreads();
    float wreg[9];
    #pragma unroll
    for (int i = 0; i < 9; ++i) wreg[i] = dw_w[d * 9 + i];
    const float bias = dw_b[d];
    #pragma unroll
    for (int i = 0; i < 4; ++i) {
        int idx = threadIdx.x + i * 256;
        int r = idx >> 5, c = idx & 31;
        float acc = bias;
        #pragma unroll
        for (int ky = 0; ky < 3; ++ky)
            #pragma unroll
            for (int kx = 0; kx < 3; ++kx)
                acc = fmaf(wreg[ky * 3 + kx], tin[r + ky][c + kx], acc);
        acc = silu_fast(acc);
        tout[r][c] = acc;
        z[(size_t)bd * LL + (h0 + r) * WW + w0 + c] = acc;
    }
    __syncthreads();
    #pragma unroll
    for (int i = 0; i < 4; ++i) {
        int idx = threadIdx.x + i * 256;
        int r = idx >> 5, c = idx & 31;   // r = w-offset, c = h-offset
        zT[(size_t)bd * LL + (w0 + r) * HH + h0 + c] = tout[c][r];
    }
}

// ---------------------------------------------------------------- kernel 3
// x-proj: per position, project 192 -> 8 for two k's. LDS-free.
// grid 2048: seg0: src z (row order, k=0,2); seg1: src zT (col order, k=1,3).
__global__ __launch_bounds__(256) void k_proj(const float* __restrict__ z,
                                              const float* __restrict__ zT,
                                              const float* __restrict__ xpw,  // (4,8,192)
                                              float* __restrict__ dtsr,       // (b,4,6,L)
                                              float* __restrict__ Bs,         // (b,4,L)
                                              float* __restrict__ Cs) {
    const int blk = blockIdx.x;           // 2048
    const int seg = blk >> 10;
    const int rest = blk & 1023;
    const int b  = rest >> 8;
    const int l0 = (rest & 255) << 6;
    const int kA = seg ? 1 : 0;
    const int kB = seg ? 3 : 2;
    const float* src = seg ? zT : z;
    const int p = threadIdx.x & 63;
    const int g = __builtin_amdgcn_readfirstlane(threadIdx.x >> 6);
    const float* sb = src + (size_t)b * D_INNER * LL + l0 + p;
    const int k  = (g < 2) ? kA : kB;
    const int e0 = (g & 1) * 4;
    const float* wrow = xpw + (size_t)(k * 8 + e0) * D_INNER;
    float a0 = 0.f, a1 = 0.f, a2 = 0.f, a3 = 0.f;
    #pragma unroll 8
    for (int dd = 0; dd < D_INNER; ++dd) {
        float v = sb[(size_t)dd * LL];
        a0 = fmaf(wrow[dd],               v, a0);
        a1 = fmaf(wrow[dd + D_INNER],     v, a1);
        a2 = fmaf(wrow[dd + 2 * D_INNER], v, a2);
        a3 = fmaf(wrow[dd + 3 * D_INNER], v, a3);
    }
    const int l = l0 + p;
    const size_t dbase = ((size_t)(b * K4 + k) * DT_RANK) * LL;
    if (e0 == 0) {
        dtsr[dbase + 0 * LL + l] = a0;
        dtsr[dbase + 1 * LL + l] = a1;
        dtsr[dbase + 2 * LL + l] = a2;
        dtsr[dbase + 3 * LL + l] = a3;
    } else {
        dtsr[dbase + 4 * LL + l] = a0;
        dtsr[dbase + 5 * LL + l] = a1;
        Bs[(size_t)(b * K4 + k) * LL + l] = a2;
        Cs[(size_t)(b * K4 + k) * LL + l] = a3;
    }
}

// ---------------------------------------------------------------- scan core
// One direction over 16384 elems, 8 chunks of 2048 (256 thr x 8). Linear
// stores always. LDSU: u comes from row-major z via LDS transpose (col order).
template <bool FWD, bool RMW, bool LDSU>
__device__ __forceinline__ void scan_core(const float* __restrict__ u_lin,
                                          const float* __restrict__ u_rm,
                                          const float* __restrict__ dtsr_k,
                                          const float* __restrict__ B_k,
                                          const float* __restrict__ C_k,
                                          const float* __restrict__ w6p,
                                          float dtbv, float A2, float Dval,
                                          float* __restrict__ dst,
                                          float* __restrict__ wPs,
                                          float* __restrict__ wSs,
                                          float* __restrict__ tile) {
    const int tid  = threadIdx.x;
    const int lane = tid & 63;
    const int wv   = tid >> 6;
    float w6[6];
    #pragma unroll
    for (int r = 0; r < 6; ++r) w6[r] = w6p[r];
    float h0 = 0.0f;
    for (int ci = 0; ci < 8; ++ci) {
        const int c  = FWD ? ci : (7 - ci);
        const int l0 = (c << 11) + (tid << 3);
        float u[8];
        if (LDSU) {
            #pragma unroll
            for (int e = 0; e < 8; ++e) {
                int idx = tid + (e << 8);
                int h = idx >> 4, w = idx & 15;
                tile[w * 132 + h] = u_rm[h * WW + (c << 4) + w];
            }
            __syncthreads();
            const int wl = tid >> 4;
            const int hb = (tid & 15) << 3;
            #pragma unroll
            for (int e = 0; e < 8; ++e) u[e] = tile[wl * 132 + hb + e];
        } else {
            float4 t0 = *(const float4*)(u_lin + l0);
            float4 t1 = *(const float4*)(u_lin + l0 + 4);
            u[0]=t0.x; u[1]=t0.y; u[2]=t0.z; u[3]=t0.w;
            u[4]=t1.x; u[5]=t1.y; u[6]=t1.z; u[7]=t1.w;
        }
        float dl[8];
        #pragma unroll
        for (int e = 0; e < 8; ++e) dl[e] = dtbv;
        #pragma unroll
        for (int r = 0; r < 6; ++r) {
            float4 t0 = *(const float4*)(dtsr_k + (size_t)r * LL + l0);
            float4 t1 = *(const float4*)(dtsr_k + (size_t)r * LL + l0 + 4);
            dl[0] = fmaf(w6[r], t0.x, dl[0]); dl[1] = fmaf(w6[r], t0.y, dl[1]);
            dl[2] = fmaf(w6[r], t0.z, dl[2]); dl[3] = fmaf(w6[r], t0.w, dl[3]);
            dl[4] = fmaf(w6[r], t1.x, dl[4]); dl[5] = fmaf(w6[r], t1.y, dl[5]);
            dl[6] = fmaf(w6[r], t1.z, dl[6]); dl[7] = fmaf(w6[r], t1.w, dl[7]);
        }
        float Bv[8], Cv[8];
        {
            float4 t0 = *(const float4*)(B_k + l0);
            float4 t1 = *(const float4*)(B_k + l0 + 4);
            Bv[0]=t0.x; Bv[1]=t0.y; Bv[2]=t0.z; Bv[3]=t0.w;
            Bv[4]=t1.x; Bv[5]=t1.y; Bv[6]=t1.z; Bv[7]=t1.w;
            t0 = *(const float4*)(C_k + l0);
            t1 = *(const float4*)(C_k + l0 + 4);
            Cv[0]=t0.x; Cv[1]=t0.y; Cv[2]=t0.z; Cv[3]=t0.w;
            Cv[4]=t1.x; Cv[5]=t1.y; Cv[6]=t1.z; Cv[7]=t1.w;
        }
        float a[8], bb[8];
        #pragma unroll
        for (int e = 0; e < 8; ++e) {
            float d1 = softplus_fast(dl[e]);
            a[e]  = fexp2_(d1 * A2);
            bb[e] = d1 * Bv[e] * u[e];
        }
        // thread-local fold in traversal order
        float P = 1.0f, S = 0.0f;
        if (FWD) {
            #pragma unroll
            for (int e = 0; e < 8; ++e) { S = fmaf(S, a[e], bb[e]); P *= a[e]; }
        } else {
            #pragma unroll
            for (int e = 7; e >= 0; --e) { S = fmaf(S, a[e], bb[e]); P *= a[e]; }
        }
        // wave-level inclusive scan (Hillis-Steele via shfl)
        #pragma unroll
        for (int s = 1; s < 64; s <<= 1) {
            float p2, s2;
            if (FWD) { p2 = __shfl_up(P, s);   s2 = __shfl_up(S, s); }
            else     { p2 = __shfl_down(P, s); s2 = __shfl_down(S, s); }
            const bool act = FWD ? (lane >= s) : (lane + s < 64);
            if (act) { S = fmaf(s2, P, S); P = p2 * P; }
        }
        __syncthreads();  // protect LDS slots (and LDSU tile) from prev readers
        if ((FWD && lane == 63) || (!FWD && lane == 0)) { wPs[wv] = P; wSs[wv] = S; }
        __syncthreads();
        // wave prefix (earlier-traversed waves)
        float Pw = 1.0f, Sw = 0.0f;
        if (FWD) { for (int w2 = 0; w2 < wv; ++w2)  { Sw = fmaf(Sw, wPs[w2], wSs[w2]); Pw *= wPs[w2]; } }
        else     { for (int w2 = 3; w2 > wv; --w2)  { Sw = fmaf(Sw, wPs[w2], wSs[w2]); Pw *= wPs[w2]; } }
        // lane-exclusive within wave
        float Pex, Sex;
        if (FWD) { Pex = __shfl_up(P, 1);   Sex = __shfl_up(S, 1);   if (lane == 0)  { Pex = 1.0f; Sex = 0.0f; } }
        else     { Pex = __shfl_down(P, 1); Sex = __shfl_down(S, 1); if (lane == 63) { Pex = 1.0f; Sex = 0.0f; } }
        float h = fmaf(Pw, h0, Sw);
        h = fmaf(Pex, h, Sex);
        // chunk total -> carry (identical on all threads)
        float Pt = 1.0f, St = 0.0f;
        if (FWD) { for (int w2 = 0; w2 < 4; ++w2)  { St = fmaf(St, wPs[w2], wSs[w2]); Pt *= wPs[w2]; } }
        else     { for (int w2 = 3; w2 >= 0; --w2) { St = fmaf(St, wPs[w2], wSs[w2]); Pt *= wPs[w2]; } }
        h0 = fmaf(Pt, h0, St);
        // replay with true incoming state
        float y[8];
        if (FWD) {
            #pragma unroll
            for (int e = 0; e < 8; ++e) { h = fmaf(a[e], h, bb[e]); y[e] = fmaf(h, Cv[e], Dval * u[e]); }
        } else {
            #pragma unroll
            for (int e = 7; e >= 0; --e) { h = fmaf(a[e], h, bb[e]); y[e] = fmaf(h, Cv[e], Dval * u[e]); }
        }
        if (!RMW) {
            *(float4*)(dst + l0)     = make_float4(y[0], y[1], y[2], y[3]);
            *(float4*)(dst + l0 + 4) = make_float4(y[4], y[5], y[6], y[7]);
        } else {
            float4 o0 = *(const float4*)(dst + l0);
            float4 o1 = *(const float4*)(dst + l0 + 4);
            o0.x += y[0]; o0.y += y[1]; o0.z += y[2]; o0.w += y[3];
            o1.x += y[4]; o1.y += y[5]; o1.z += y[6]; o1.w += y[7];
            *(float4*)(dst + l0)     = o0;
            *(float4*)(dst + l0 + 4) = o1;
        }
    }
}

// scanA: half0 = fwd-row (k0, store y_r), half1 = bwd-col (k3, store zT in place)
__global__ __launch_bounds__(256) void k_scanA(const float* __restrict__ z,
                                               float* __restrict__ zT,
                                               float* __restrict__ y_r,
                                               const float* __restrict__ dtsr,
                                               const float* __restrict__ Bs,
                                               const float* __restrict__ Cs,
                                               const float* __restrict__ dtw,
                                               const float* __restrict__ dtb,
                                               const float* __restrict__ A_logs,
                                               const float* __restrict__ Ds) {
    __shared__ float wPs[4], wSs[4];
    const int blk = blockIdx.x;           // 1536
    const int half = blk >= 768;
    const int bd = half ? blk - 768 : blk;
    const int b = bd / D_INNER, d = bd - b * D_INNER;
    const int k = half ? 3 : 0;
    const int kd = k * D_INNER + d;
    const float* dk = dtsr + ((size_t)(b * K4 + k) * DT_RANK) * LL;
    const float* Bk = Bs + (size_t)(b * K4 + k) * LL;
    const float* Ck = Cs + (size_t)(b * K4 + k) * LL;
    const float* w6p = dtw + (size_t)kd * 6;
    const float A2 = -expf(A_logs[kd]) * LOG2E;
    if (!half)
        scan_core<true, false, false>(z + (size_t)bd * LL, nullptr, dk, Bk, Ck, w6p,
                                      dtb[kd], A2, Ds[kd], y_r + (size_t)bd * LL,
                                      wPs, wSs, nullptr);
    else
        scan_core<false, false, false>(zT + (size_t)bd * LL, nullptr, dk, Bk, Ck, w6p,
                                       dtb[kd], A2, Ds[kd], zT + (size_t)bd * LL,
                                       wPs, wSs, nullptr);
}

// scanB: half0 = bwd-row (k2, RMW y_r), half1 = fwd-col (k1, u via LDS transpose
// of z, RMW zT which holds col-major y)
__global__ __launch_bounds__(256) void k_scanB(const float* __restrict__ z,
                                               float* __restrict__ zT,
                                               float* __restrict__ y_r,
                                               const float* __restrict__ dtsr,
                                               const float* __restrict__ Bs,
                                               const float* __restrict__ Cs,
                                               const float* __restrict__ dtw,
                                               const float* __restrict__ dtb,
                                               const float* __restrict__ A_logs,
                                               const float* __restrict__ Ds) {
    __shared__ float wPs[4], wSs[4];
    __shared__ float tile[16 * 132];
    const int blk = blockIdx.x;           // 1536
    const int half = blk >= 768;
    const int bd = half ? blk - 768 : blk;
    const int b = bd / D_INNER, d = bd - b * D_INNER;
    const int k = half ? 1 : 2;
    const int kd = k * D_INNER + d;
    const float* dk = dtsr + ((size_t)(b * K4 + k) * DT_RANK) * LL;
    const float* Bk = Bs + (size_t)(b * K4 + k) * LL;
    const float* Ck = Cs + (size_t)(b * K4 + k) * LL;
    const float* w6p = dtw + (size_t)kd * 6;
    const float A2 = -expf(A_logs[kd]) * LOG2E;
    if (!half)
        scan_core<false, true, false>(z + (size_t)bd * LL, nullptr, dk, Bk, Ck, w6p,
                                      dtb[kd], A2, Ds[kd], y_r + (size_t)bd * LL,
                                      wPs, wSs, nullptr);
    else
        scan_core<true, true, true>(nullptr, z + (size_t)bd * LL, dk, Bk, Ck, w6p,
                                    dtb[kd], A2, Ds[kd], zT + (size_t)bd * LL,
                                    wPs, wSs, tile);
}

// ---------------------------------------------------------------- merge
// y_r[b,d,h*W+w] += y_c[b,d,w*H+h]   (y_c lives in zT, col-major)
__global__ __launch_bounds__(256) void k_taddT(const float* __restrict__ ym2,
                                               float* __restrict__ ym) {
    __shared__ float t[32][33];
    const int blk  = blockIdx.x;          // 768*16
    const int tile = blk & 15;
    const int bd   = blk >> 4;
    const int h0 = (tile >> 2) << 5, w0 = (tile & 3) << 5;
    const float* s = ym2 + (size_t)bd * LL;
    float* o = ym + (size_t)bd * LL;
    for (int i = threadIdx.x; i < 1024; i += 256) {
        int r = i >> 5, c = i & 31;       // r = w-off, c = h-off
        t[r][c] = s[(w0 + r) * HH + h0 + c];
    }
    __syncthreads();
    for (int i = threadIdx.x; i < 1024; i += 256) {
        int r = i >> 5, c = i & 31;       // r = h-off, c = w-off
        o[(h0 + r) * WW + w0 + c] += t[c][r];
    }
}

// ---------------------------------------------------------------- kernel 8
// per pixel: LayerNorm over 192 channels, then 192->96 projection + bias.
// 8 waves/block: cooperative stats (LDS reduce), then each wave emits 12
// output channels. Grid 1024 x 512 thr = 100% occupancy capacity.
__global__ __launch_bounds__(512) void k_lnout(const float* __restrict__ ym,
                                               const float* __restrict__ ln_w,
                                               const float* __restrict__ ln_b,
                                               const float* __restrict__ out_w,  // (96,192)
                                               const float* __restrict__ out_b,
                                               float* __restrict__ out) {
    __shared__ float red1[8][64];
    __shared__ float red2[8][64];
    const int blk = blockIdx.x;           // 1024
    const int b  = blk >> 8;
    const int l0 = (blk & 255) << 6;
    const int p = threadIdx.x & 63;
    const int g = __builtin_amdgcn_readfirstlane(threadIdx.x >> 6);  // 0..7
    const float* vm = ym + (size_t)b * D_INNER * LL + l0 + p;
    // pass 1: wave g sums channels [g*24, g*24+24) for its 64 pixels
    float s1 = 0.f, s2 = 0.f;
    #pragma unroll 8
    for (int j = 0; j < 24; ++j) {
        float v = vm[(size_t)(g * 24 + j) * LL];
        s1 += v;
        s2 = fmaf(v, v, s2);
    }
    red1[g][p] = s1;
    red2[g][p] = s2;
    __syncthreads();
    float t1 = 0.f, t2 = 0.f;
    #pragma unroll
    for (int j = 0; j < 8; ++j) { t1 += red1[j][p]; t2 += red2[j][p]; }
    const float mu = t1 * (1.0f / 192.0f);
    const float rs = rsqrtf(t2 * (1.0f / 192.0f) - mu * mu + 1e-5f);
    // pass 2: normalize on the fly, wave g accumulates channels g*12..g*12+11
    float acc[12];
    #pragma unroll
    for (int cb = 0; cb < 12; ++cb) acc[cb] = 0.f;
    const float* wq = out_w + (size_t)g * 12 * D_INNER;
    #pragma unroll 8
    for (int dd = 0; dd < D_INNER; ++dd) {
        float v = vm[(size_t)dd * LL];
        float yn = fmaf((v - mu) * rs, ln_w[dd], ln_b[dd]);
        #pragma unroll
        for (int cb = 0; cb < 12; ++cb)
            acc[cb] = fmaf(wq[(size_t)cb * D_INNER + dd], yn, acc[cb]);
    }
    float* ob = out + (size_t)b * D_MODEL * LL + l0 + p;
    #pragma unroll
    for (int cb = 0; cb < 12; ++cb) {
        int cc = g * 12 + cb;
        ob[(size_t)cc * LL] = acc[cb] + out_b[cc];
    }
}

// ----------------------------------------------------------------
extern "C" void kernel_launch(void* const* d_in, const int* in_sizes, int n_in,
                              void* d_out, int out_size, void* d_ws, size_t ws_size,
                              hipStream_t stream) {
    (void)in_sizes; (void)n_in; (void)out_size; (void)ws_size;
    const float* x      = (const float*)d_in[0];
    const float* in_w   = (const float*)d_in[1];
    const float* in_b   = (const float*)d_in[2];
    const float* dw_w   = (const float*)d_in[3];
    const float* dw_b   = (const float*)d_in[4];
    const float* xpw    = (const float*)d_in[5];
    const float* dtw    = (const float*)d_in[6];
    const float* dtb    = (const float*)d_in[7];
    const float* A_logs = (const float*)d_in[8];
    const float* Ds     = (const float*)d_in[9];
    const float* ln_w   = (const float*)d_in[10];
    const float* ln_b   = (const float*)d_in[11];
    const float* out_w  = (const float*)d_in[12];
    const float* out_b  = (const float*)d_in[13];
    float* out = (float*)d_out;

    float* ws = (float*)d_ws;
    const size_t A1 = (size_t)BSZ * D_INNER * LL;       // 12.58M floats
    float* z0   = ws;                                   // reused as y_r after conv
    float* z    = ws + A1;
    float* zT   = ws + 2 * A1;                          // reused in-place as y_c (col-major)
    float* dtsr = ws + 3 * A1;                          // (b,4,6,L)
    float* BsP  = dtsr + (size_t)BSZ * K4 * DT_RANK * LL;
    float* CsP  = BsP + (size_t)BSZ * K4 * LL;
    // total ws use: 3*A1 + 2.1M floats ~ 159 MB

    float* y_r = z0;

    k_inproj<<<1024, 256, 0, stream>>>(x, in_w, in_b, z0);
    k_dwconv<<<BSZ * D_INNER * 16, 256, 0, stream>>>(z0, dw_w, dw_b, z, zT);
    k_proj<<<2048, 256, 0, stream>>>(z, zT, xpw, dtsr, BsP, CsP);
    k_scanA<<<1536, 256, 0, stream>>>(z, zT, y_r, dtsr, BsP, CsP, dtw, dtb, A_logs, Ds);
    k_scanB<<<1536, 256, 0, stream>>>(z, zT, y_r, dtsr, BsP, CsP, dtw, dtb, A_logs, Ds);
    k_taddT<<<BSZ * D_INNER * 16, 256, 0, stream>>>(zT, y_r);
    k_lnout<<<1024, 512, 0, stream>>>(y_r, ln_w, ln_b, out_w, out_b, out);
}

// Round 6
// 397.688 us; speedup vs baseline: 1.1276x; 1.1276x over previous
//
#include <hip/hip_runtime.h>
#include <math.h>

#define D_MODEL 96
#define D_INNER 192
#define DT_RANK 6
#define K4      4
#define BSZ     4
#define HH      128
#define WW      128
#define LL      16384  // HH*WW

#define LOG2E 1.4426950408889634f
#define LN2   0.6931471805599453f

#if __has_builtin(__builtin_amdgcn_exp2f)
__device__ __forceinline__ float fexp2_(float x){ return __builtin_amdgcn_exp2f(x); }
#else
__device__ __forceinline__ float fexp2_(float x){ return exp2f(x); }
#endif
#if __has_builtin(__builtin_amdgcn_logf)
__device__ __forceinline__ float flog2_(float x){ return __builtin_amdgcn_logf(x); }
#else
__device__ __forceinline__ float flog2_(float x){ return log2f(x); }
#endif
#if __has_builtin(__builtin_amdgcn_rcpf)
__device__ __forceinline__ float frcp_(float x){ return __builtin_amdgcn_rcpf(x); }
#else
__device__ __forceinline__ float frcp_(float x){ return 1.0f/x; }
#endif

__device__ __forceinline__ float softplus_fast(float x){
    return fmaxf(x, 0.0f) + LN2 * flog2_(1.0f + fexp2_(-LOG2E * fabsf(x)));
}
__device__ __forceinline__ float silu_fast(float x){
    return x * frcp_(1.0f + fexp2_(-LOG2E * x));
}

// ---------------------------------------------------------------- kernel 1
// z0[b,d,l] = sum_c in_w[d,c] * x[b,c,l] + in_b[d]
// 8 waves/block; wave g computes channels g*24..g*24+23 in 3 passes of 8
// accumulators. LDS-free; the 24KB x tile stays L1-hot across passes/waves.
__global__ __launch_bounds__(512) void k_inproj(const float* __restrict__ x,
                                                const float* __restrict__ in_w,
                                                const float* __restrict__ in_b,
                                                float* __restrict__ z0) {
    const int blk = blockIdx.x;           // 1024 = 4 b * 256 chunks
    const int b  = blk >> 8;
    const int l0 = (blk & 255) << 6;
    const int p = threadIdx.x & 63;
    const int g = __builtin_amdgcn_readfirstlane(threadIdx.x >> 6);  // 0..7
    const float* xb = x + (size_t)b * D_MODEL * LL + l0 + p;
    float* zb = z0 + (size_t)b * D_INNER * LL + l0 + p;
    for (int jb = 0; jb < 3; ++jb) {
        const int d0 = g * 24 + jb * 8;
        float acc[8];
        #pragma unroll
        for (int j = 0; j < 8; ++j) acc[j] = in_b[d0 + j];
        const float* w0 = in_w + (size_t)d0 * D_MODEL;
        #pragma unroll 4
        for (int c = 0; c < D_MODEL; ++c) {
            float v = xb[(size_t)c * LL];
            #pragma unroll
            for (int j = 0; j < 8; ++j)
                acc[j] = fmaf(w0[c + j * D_MODEL], v, acc[j]);
        }
        #pragma unroll
        for (int j = 0; j < 8; ++j) zb[(size_t)(d0 + j) * LL] = acc[j];
    }
}

// ---------------------------------------------------------------- kernel 2
// depthwise 3x3 SAME conv + bias + SiLU -> z (row-major) and zT (transposed)
__global__ __launch_bounds__(256) void k_dwconv(const float* __restrict__ z0,
                                                const float* __restrict__ dw_w,
                                                const float* __restrict__ dw_b,
                                                float* __restrict__ z,
                                                float* __restrict__ zT) {
    __shared__ float tin[34][34];
    __shared__ float tout[32][33];
    const int blk  = blockIdx.x;          // 768*16
    const int tile = blk & 15;
    const int bd   = blk >> 4;            // b*192 + d
    const int d    = bd % D_INNER;
    const int h0 = (tile >> 2) << 5, w0 = (tile & 3) << 5;
    const float* src = z0 + (size_t)bd * LL;
    for (int i = threadIdx.x; i < 34 * 34; i += 256) {
        int r = i / 34, c = i - r * 34;
        int hh = h0 + r - 1, ww = w0 + c - 1;
        float v = 0.0f;
        if (hh >= 0 && hh < HH && ww >= 0 && ww < WW) v = src[hh * WW + ww];
        tin[r][c] = v;
    }
    __syncthreads();
    float wreg[9];
    #pragma unroll
    for (int i = 0; i < 9; ++i) wreg[i] = dw_w[d * 9 + i];
    const float bias = dw_b[d];
    #pragma unroll
    for (int i = 0; i < 4; ++i) {
        int idx = threadIdx.x + i * 256;
        int r = idx >> 5, c = idx & 31;
        float acc = bias;
        #pragma unroll
        for (int ky = 0; ky < 3; ++ky)
            #pragma unroll
            for (int kx = 0; kx < 3; ++kx)
                acc = fmaf(wreg[ky * 3 + kx], tin[r + ky][c + kx], acc);
        acc = silu_fast(acc);
        tout[r][c] = acc;
        z[(size_t)bd * LL + (h0 + r) * WW + w0 + c] = acc;
    }
    __syncthreads();
    #pragma unroll
    for (int i = 0; i < 4; ++i) {
        int idx = threadIdx.x + i * 256;
        int r = idx >> 5, c = idx & 31;   // r = w-offset, c = h-offset
        zT[(size_t)bd * LL + (w0 + r) * HH + h0 + c] = tout[c][r];
    }
}

// ---------------------------------------------------------------- kernel 3
// x-proj: per position, project 192 -> 8 for two k's. LDS-free.
// grid 2048: seg0: src z (row order, k=0,2); seg1: src zT (col order, k=1,3).
__global__ __launch_bounds__(256) void k_proj(const float* __restrict__ z,
                                              const float* __restrict__ zT,
                                              const float* __restrict__ xpw,  // (4,8,192)
                                              float* __restrict__ dtsr,       // (b,4,6,L)
                                              float* __restrict__ Bs,         // (b,4,L)
                                              float* __restrict__ Cs) {
    const int blk = blockIdx.x;           // 2048
    const int seg = blk >> 10;
    const int rest = blk & 1023;
    const int b  = rest >> 8;
    const int l0 = (rest & 255) << 6;
    const int kA = seg ? 1 : 0;
    const int kB = seg ? 3 : 2;
    const float* src = seg ? zT : z;
    const int p = threadIdx.x & 63;
    const int g = __builtin_amdgcn_readfirstlane(threadIdx.x >> 6);
    const float* sb = src + (size_t)b * D_INNER * LL + l0 + p;
    const int k  = (g < 2) ? kA : kB;
    const int e0 = (g & 1) * 4;
    const float* wrow = xpw + (size_t)(k * 8 + e0) * D_INNER;
    float a0 = 0.f, a1 = 0.f, a2 = 0.f, a3 = 0.f;
    #pragma unroll 8
    for (int dd = 0; dd < D_INNER; ++dd) {
        float v = sb[(size_t)dd * LL];
        a0 = fmaf(wrow[dd],               v, a0);
        a1 = fmaf(wrow[dd + D_INNER],     v, a1);
        a2 = fmaf(wrow[dd + 2 * D_INNER], v, a2);
        a3 = fmaf(wrow[dd + 3 * D_INNER], v, a3);
    }
    const int l = l0 + p;
    const size_t dbase = ((size_t)(b * K4 + k) * DT_RANK) * LL;
    if (e0 == 0) {
        dtsr[dbase + 0 * LL + l] = a0;
        dtsr[dbase + 1 * LL + l] = a1;
        dtsr[dbase + 2 * LL + l] = a2;
        dtsr[dbase + 3 * LL + l] = a3;
    } else {
        dtsr[dbase + 4 * LL + l] = a0;
        dtsr[dbase + 5 * LL + l] = a1;
        Bs[(size_t)(b * K4 + k) * LL + l] = a2;
        Cs[(size_t)(b * K4 + k) * LL + l] = a3;
    }
}

// ---------------------------------------------------------------- scan core
// One direction over 16384 elems, 8 chunks of 2048 (256 thr x 8). Linear
// stores always. LDSU: u comes from row-major z via LDS transpose (col order).
// Non-LDSU path software-pipelines u/B/C loads one chunk ahead so HBM/L2
// latency overlaps the delta/transcendental/shuffle phase.
template <bool FWD, bool RMW, bool LDSU>
__device__ __forceinline__ void scan_core(const float* __restrict__ u_lin,
                                          const float* __restrict__ u_rm,
                                          const float* __restrict__ dtsr_k,
                                          const float* __restrict__ B_k,
                                          const float* __restrict__ C_k,
                                          const float* __restrict__ w6p,
                                          float dtbv, float A2, float Dval,
                                          float* __restrict__ dst,
                                          float* __restrict__ wPs,
                                          float* __restrict__ wSs,
                                          float* __restrict__ tile) {
    const int tid  = threadIdx.x;
    const int lane = tid & 63;
    const int wv   = tid >> 6;
    float w6[6];
    #pragma unroll
    for (int r = 0; r < 6; ++r) w6[r] = w6p[r];
    float h0 = 0.0f;
    float4 pu0, pu1, pB0, pB1, pC0, pC1;
    if (!LDSU) {
        const int c0 = FWD ? 0 : 7;
        const int q0 = (c0 << 11) + (tid << 3);
        pu0 = *(const float4*)(u_lin + q0);
        pu1 = *(const float4*)(u_lin + q0 + 4);
        pB0 = *(const float4*)(B_k + q0);
        pB1 = *(const float4*)(B_k + q0 + 4);
        pC0 = *(const float4*)(C_k + q0);
        pC1 = *(const float4*)(C_k + q0 + 4);
    }
    for (int ci = 0; ci < 8; ++ci) {
        const int c  = FWD ? ci : (7 - ci);
        const int l0 = (c << 11) + (tid << 3);
        float u[8], Bv[8], Cv[8];
        if (LDSU) {
            #pragma unroll
            for (int e = 0; e < 8; ++e) {
                int idx = tid + (e << 8);
                int h = idx >> 4, w = idx & 15;
                tile[w * 132 + h] = u_rm[h * WW + (c << 4) + w];
            }
            __syncthreads();
            const int wl = tid >> 4;
            const int hb = (tid & 15) << 3;
            #pragma unroll
            for (int e = 0; e < 8; ++e) u[e] = tile[wl * 132 + hb + e];
            float4 t0 = *(const float4*)(B_k + l0);
            float4 t1 = *(const float4*)(B_k + l0 + 4);
            Bv[0]=t0.x; Bv[1]=t0.y; Bv[2]=t0.z; Bv[3]=t0.w;
            Bv[4]=t1.x; Bv[5]=t1.y; Bv[6]=t1.z; Bv[7]=t1.w;
            t0 = *(const float4*)(C_k + l0);
            t1 = *(const float4*)(C_k + l0 + 4);
            Cv[0]=t0.x; Cv[1]=t0.y; Cv[2]=t0.z; Cv[3]=t0.w;
            Cv[4]=t1.x; Cv[5]=t1.y; Cv[6]=t1.z; Cv[7]=t1.w;
        } else {
            u[0]=pu0.x; u[1]=pu0.y; u[2]=pu0.z; u[3]=pu0.w;
            u[4]=pu1.x; u[5]=pu1.y; u[6]=pu1.z; u[7]=pu1.w;
            Bv[0]=pB0.x; Bv[1]=pB0.y; Bv[2]=pB0.z; Bv[3]=pB0.w;
            Bv[4]=pB1.x; Bv[5]=pB1.y; Bv[6]=pB1.z; Bv[7]=pB1.w;
            Cv[0]=pC0.x; Cv[1]=pC0.y; Cv[2]=pC0.z; Cv[3]=pC0.w;
            Cv[4]=pC1.x; Cv[5]=pC1.y; Cv[6]=pC1.z; Cv[7]=pC1.w;
            if (ci < 7) {
                const int cn = FWD ? (ci + 1) : (6 - ci);
                const int qn = (cn << 11) + (tid << 3);
                pu0 = *(const float4*)(u_lin + qn);
                pu1 = *(const float4*)(u_lin + qn + 4);
                pB0 = *(const float4*)(B_k + qn);
                pB1 = *(const float4*)(B_k + qn + 4);
                pC0 = *(const float4*)(C_k + qn);
                pC1 = *(const float4*)(C_k + qn + 4);
            }
        }
        float dl[8];
        #pragma unroll
        for (int e = 0; e < 8; ++e) dl[e] = dtbv;
        #pragma unroll
        for (int r = 0; r < 6; ++r) {
            float4 t0 = *(const float4*)(dtsr_k + (size_t)r * LL + l0);
            float4 t1 = *(const float4*)(dtsr_k + (size_t)r * LL + l0 + 4);
            dl[0] = fmaf(w6[r], t0.x, dl[0]); dl[1] = fmaf(w6[r], t0.y, dl[1]);
            dl[2] = fmaf(w6[r], t0.z, dl[2]); dl[3] = fmaf(w6[r], t0.w, dl[3]);
            dl[4] = fmaf(w6[r], t1.x, dl[4]); dl[5] = fmaf(w6[r], t1.y, dl[5]);
            dl[6] = fmaf(w6[r], t1.z, dl[6]); dl[7] = fmaf(w6[r], t1.w, dl[7]);
        }
        float a[8], bb[8];
        #pragma unroll
        for (int e = 0; e < 8; ++e) {
            float d1 = softplus_fast(dl[e]);
            a[e]  = fexp2_(d1 * A2);
            bb[e] = d1 * Bv[e] * u[e];
        }
        // thread-local fold in traversal order
        float P = 1.0f, S = 0.0f;
        if (FWD) {
            #pragma unroll
            for (int e = 0; e < 8; ++e) { S = fmaf(S, a[e], bb[e]); P *= a[e]; }
        } else {
            #pragma unroll
            for (int e = 7; e >= 0; --e) { S = fmaf(S, a[e], bb[e]); P *= a[e]; }
        }
        // wave-level inclusive scan (Hillis-Steele via shfl)
        #pragma unroll
        for (int s = 1; s < 64; s <<= 1) {
            float p2, s2;
            if (FWD) { p2 = __shfl_up(P, s);   s2 = __shfl_up(S, s); }
            else     { p2 = __shfl_down(P, s); s2 = __shfl_down(S, s); }
            const bool act = FWD ? (lane >= s) : (lane + s < 64);
            if (act) { S = fmaf(s2, P, S); P = p2 * P; }
        }
        __syncthreads();  // protect LDS slots (and LDSU tile) from prev readers
        if ((FWD && lane == 63) || (!FWD && lane == 0)) { wPs[wv] = P; wSs[wv] = S; }
        __syncthreads();
        // wave prefix (earlier-traversed waves)
        float Pw = 1.0f, Sw = 0.0f;
        if (FWD) { for (int w2 = 0; w2 < wv; ++w2)  { Sw = fmaf(Sw, wPs[w2], wSs[w2]); Pw *= wPs[w2]; } }
        else     { for (int w2 = 3; w2 > wv; --w2)  { Sw = fmaf(Sw, wPs[w2], wSs[w2]); Pw *= wPs[w2]; } }
        // lane-exclusive within wave
        float Pex, Sex;
        if (FWD) { Pex = __shfl_up(P, 1);   Sex = __shfl_up(S, 1);   if (lane == 0)  { Pex = 1.0f; Sex = 0.0f; } }
        else     { Pex = __shfl_down(P, 1); Sex = __shfl_down(S, 1); if (lane == 63) { Pex = 1.0f; Sex = 0.0f; } }
        float h = fmaf(Pw, h0, Sw);
        h = fmaf(Pex, h, Sex);
        // chunk total -> carry (identical on all threads)
        float Pt = 1.0f, St = 0.0f;
        if (FWD) { for (int w2 = 0; w2 < 4; ++w2)  { St = fmaf(St, wPs[w2], wSs[w2]); Pt *= wPs[w2]; } }
        else     { for (int w2 = 3; w2 >= 0; --w2) { St = fmaf(St, wPs[w2], wSs[w2]); Pt *= wPs[w2]; } }
        h0 = fmaf(Pt, h0, St);
        // replay with true incoming state
        float y[8];
        if (FWD) {
            #pragma unroll
            for (int e = 0; e < 8; ++e) { h = fmaf(a[e], h, bb[e]); y[e] = fmaf(h, Cv[e], Dval * u[e]); }
        } else {
            #pragma unroll
            for (int e = 7; e >= 0; --e) { h = fmaf(a[e], h, bb[e]); y[e] = fmaf(h, Cv[e], Dval * u[e]); }
        }
        if (!RMW) {
            *(float4*)(dst + l0)     = make_float4(y[0], y[1], y[2], y[3]);
            *(float4*)(dst + l0 + 4) = make_float4(y[4], y[5], y[6], y[7]);
        } else {
            float4 o0 = *(const float4*)(dst + l0);
            float4 o1 = *(const float4*)(dst + l0 + 4);
            o0.x += y[0]; o0.y += y[1]; o0.z += y[2]; o0.w += y[3];
            o1.x += y[4]; o1.y += y[5]; o1.z += y[6]; o1.w += y[7];
            *(float4*)(dst + l0)     = o0;
            *(float4*)(dst + l0 + 4) = o1;
        }
    }
}

// scanA: half0 = fwd-row (k0, store y_r), half1 = bwd-col (k3, store zT in place)
__global__ __launch_bounds__(256) void k_scanA(const float* __restrict__ z,
                                               float* __restrict__ zT,
                                               float* __restrict__ y_r,
                                               const float* __restrict__ dtsr,
                                               const float* __restrict__ Bs,
                                               const float* __restrict__ Cs,
                                               const float* __restrict__ dtw,
                                               const float* __restrict__ dtb,
                                               const float* __restrict__ A_logs,
                                               const float* __restrict__ Ds) {
    __shared__ float wPs[4], wSs[4];
    const int blk = blockIdx.x;           // 1536
    const int half = blk >= 768;
    const int bd = half ? blk - 768 : blk;
    const int b = bd / D_INNER, d = bd - b * D_INNER;
    const int k = half ? 3 : 0;
    const int kd = k * D_INNER + d;
    const float* dk = dtsr + ((size_t)(b * K4 + k) * DT_RANK) * LL;
    const float* Bk = Bs + (size_t)(b * K4 + k) * LL;
    const float* Ck = Cs + (size_t)(b * K4 + k) * LL;
    const float* w6p = dtw + (size_t)kd * 6;
    const float A2 = -expf(A_logs[kd]) * LOG2E;
    if (!half)
        scan_core<true, false, false>(z + (size_t)bd * LL, nullptr, dk, Bk, Ck, w6p,
                                      dtb[kd], A2, Ds[kd], y_r + (size_t)bd * LL,
                                      wPs, wSs, nullptr);
    else
        scan_core<false, false, false>(zT + (size_t)bd * LL, nullptr, dk, Bk, Ck, w6p,
                                       dtb[kd], A2, Ds[kd], zT + (size_t)bd * LL,
                                       wPs, wSs, nullptr);
}

// scanB: half0 = bwd-row (k2, RMW y_r), half1 = fwd-col (k1, u via LDS transpose
// of z, RMW zT which holds col-major y)
__global__ __launch_bounds__(256) void k_scanB(const float* __restrict__ z,
                                               float* __restrict__ zT,
                                               float* __restrict__ y_r,
                                               const float* __restrict__ dtsr,
                                               const float* __restrict__ Bs,
                                               const float* __restrict__ Cs,
                                               const float* __restrict__ dtw,
                                               const float* __restrict__ dtb,
                                               const float* __restrict__ A_logs,
                                               const float* __restrict__ Ds) {
    __shared__ float wPs[4], wSs[4];
    __shared__ float tile[16 * 132];
    const int blk = blockIdx.x;           // 1536
    const int half = blk >= 768;
    const int bd = half ? blk - 768 : blk;
    const int b = bd / D_INNER, d = bd - b * D_INNER;
    const int k = half ? 1 : 2;
    const int kd = k * D_INNER + d;
    const float* dk = dtsr + ((size_t)(b * K4 + k) * DT_RANK) * LL;
    const float* Bk = Bs + (size_t)(b * K4 + k) * LL;
    const float* Ck = Cs + (size_t)(b * K4 + k) * LL;
    const float* w6p = dtw + (size_t)kd * 6;
    const float A2 = -expf(A_logs[kd]) * LOG2E;
    if (!half)
        scan_core<false, true, false>(z + (size_t)bd * LL, nullptr, dk, Bk, Ck, w6p,
                                      dtb[kd], A2, Ds[kd], y_r + (size_t)bd * LL,
                                      wPs, wSs, nullptr);
    else
        scan_core<true, true, true>(nullptr, z + (size_t)bd * LL, dk, Bk, Ck, w6p,
                                    dtb[kd], A2, Ds[kd], zT + (size_t)bd * LL,
                                    wPs, wSs, tile);
}

// ---------------------------------------------------------------- merge
// y_r[b,d,h*W+w] += y_c[b,d,w*H+h]   (y_c lives in zT, col-major)
__global__ __launch_bounds__(256) void k_taddT(const float* __restrict__ ym2,
                                               float* __restrict__ ym) {
    __shared__ float t[32][33];
    const int blk  = blockIdx.x;          // 768*16
    const int tile = blk & 15;
    const int bd   = blk >> 4;
    const int h0 = (tile >> 2) << 5, w0 = (tile & 3) << 5;
    const float* s = ym2 + (size_t)bd * LL;
    float* o = ym + (size_t)bd * LL;
    for (int i = threadIdx.x; i < 1024; i += 256) {
        int r = i >> 5, c = i & 31;       // r = w-off, c = h-off
        t[r][c] = s[(w0 + r) * HH + h0 + c];
    }
    __syncthreads();
    for (int i = threadIdx.x; i < 1024; i += 256) {
        int r = i >> 5, c = i & 31;       // r = h-off, c = w-off
        o[(h0 + r) * WW + w0 + c] += t[c][r];
    }
}

// ---------------------------------------------------------------- kernel 8
// per pixel: LayerNorm over 192 channels, then 192->96 projection + bias.
// 8 waves/block: cooperative stats (LDS reduce), then each wave emits 12
// output channels. Grid 1024 x 512 thr = 100% occupancy capacity.
__global__ __launch_bounds__(512) void k_lnout(const float* __restrict__ ym,
                                               const float* __restrict__ ln_w,
                                               const float* __restrict__ ln_b,
                                               const float* __restrict__ out_w,  // (96,192)
                                               const float* __restrict__ out_b,
                                               float* __restrict__ out) {
    __shared__ float red1[8][64];
    __shared__ float red2[8][64];
    const int blk = blockIdx.x;           // 1024
    const int b  = blk >> 8;
    const int l0 = (blk & 255) << 6;
    const int p = threadIdx.x & 63;
    const int g = __builtin_amdgcn_readfirstlane(threadIdx.x >> 6);  // 0..7
    const float* vm = ym + (size_t)b * D_INNER * LL + l0 + p;
    // pass 1: wave g sums channels [g*24, g*24+24) for its 64 pixels
    float s1 = 0.f, s2 = 0.f;
    #pragma unroll 8
    for (int j = 0; j < 24; ++j) {
        float v = vm[(size_t)(g * 24 + j) * LL];
        s1 += v;
        s2 = fmaf(v, v, s2);
    }
    red1[g][p] = s1;
    red2[g][p] = s2;
    __syncthreads();
    float t1 = 0.f, t2 = 0.f;
    #pragma unroll
    for (int j = 0; j < 8; ++j) { t1 += red1[j][p]; t2 += red2[j][p]; }
    const float mu = t1 * (1.0f / 192.0f);
    const float rs = rsqrtf(t2 * (1.0f / 192.0f) - mu * mu + 1e-5f);
    // pass 2: normalize on the fly, wave g accumulates channels g*12..g*12+11
    float acc[12];
    #pragma unroll
    for (int cb = 0; cb < 12; ++cb) acc[cb] = 0.f;
    const float* wq = out_w + (size_t)g * 12 * D_INNER;
    #pragma unroll 8
    for (int dd = 0; dd < D_INNER; ++dd) {
        float v = vm[(size_t)dd * LL];
        float yn = fmaf((v - mu) * rs, ln_w[dd], ln_b[dd]);
        #pragma unroll
        for (int cb = 0; cb < 12; ++cb)
            acc[cb] = fmaf(wq[(size_t)cb * D_INNER + dd], yn, acc[cb]);
    }
    float* ob = out + (size_t)b * D_MODEL * LL + l0 + p;
    #pragma unroll
    for (int cb = 0; cb < 12; ++cb) {
        int cc = g * 12 + cb;
        ob[(size_t)cc * LL] = acc[cb] + out_b[cc];
    }
}

// ----------------------------------------------------------------
extern "C" void kernel_launch(void* const* d_in, const int* in_sizes, int n_in,
                              void* d_out, int out_size, void* d_ws, size_t ws_size,
                              hipStream_t stream) {
    (void)in_sizes; (void)n_in; (void)out_size; (void)ws_size;
    const float* x      = (const float*)d_in[0];
    const float* in_w   = (const float*)d_in[1];
    const float* in_b   = (const float*)d_in[2];
    const float* dw_w   = (const float*)d_in[3];
    const float* dw_b   = (const float*)d_in[4];
    const float* xpw    = (const float*)d_in[5];
    const float* dtw    = (const float*)d_in[6];
    const float* dtb    = (const float*)d_in[7];
    const float* A_logs = (const float*)d_in[8];
    const float* Ds     = (const float*)d_in[9];
    const float* ln_w   = (const float*)d_in[10];
    const float* ln_b   = (const float*)d_in[11];
    const float* out_w  = (const float*)d_in[12];
    const float* out_b  = (const float*)d_in[13];
    float* out = (float*)d_out;

    float* ws = (float*)d_ws;
    const size_t A1 = (size_t)BSZ * D_INNER * LL;       // 12.58M floats
    float* z0   = ws;                                   // reused as y_r after conv
    float* z    = ws + A1;
    float* zT   = ws + 2 * A1;                          // reused in-place as y_c (col-major)
    float* dtsr = ws + 3 * A1;                          // (b,4,6,L)
    float* BsP  = dtsr + (size_t)BSZ * K4 * DT_RANK * LL;
    float* CsP  = BsP + (size_t)BSZ * K4 * LL;
    // total ws use: 3*A1 + 2.1M floats ~ 159 MB

    float* y_r = z0;

    k_inproj<<<1024, 512, 0, stream>>>(x, in_w, in_b, z0);
    k_dwconv<<<BSZ * D_INNER * 16, 256, 0, stream>>>(z0, dw_w, dw_b, z, zT);
    k_proj<<<2048, 256, 0, stream>>>(z, zT, xpw, dtsr, BsP, CsP);
    k_scanA<<<1536, 256, 0, stream>>>(z, zT, y_r, dtsr, BsP, CsP, dtw, dtb, A_logs, Ds);
    k_scanB<<<1536, 256, 0, stream>>>(z, zT, y_r, dtsr, BsP, CsP, dtw, dtb, A_logs, Ds);
    k_taddT<<<BSZ * D_INNER * 16, 256, 0, stream>>>(zT, y_r);
    k_lnout<<<1024, 512, 0, stream>>>(y_r, ln_w, ln_b, out_w, out_b, out);
}